// Round 11
// baseline (253.942 us; speedup 1.0000x reference)
//
#include <hip/hip_runtime.h>

#define NSTEPS 20
#define ALPHA  0.9f
#define VTH    1.0f
#define GSOMA  0.3f
#define ISCALE 0.5f

#define NOR  21
#define NORN 42
#define NLN  56
#define NPN  42
#define NKC  2000
#define NOD  34

#define TPB  256
#define KPER 8   // KCs per consumer thread: 250 * 8 = 2000

// One block = one batch row.
// Prologue (wave 0 only, sequential register-light stages, masks via LDS):
//   S1 : ORN+LN recurrence  (wOl[42] regs)        -> sAB[t] = {mOrn, mLn}
//   S2a: PN excitation/step (wOp[42] regs)        -> apn[20] regs
//   S2b: PN recurrence      (wLp[56]+apn[20] regs)-> sPN[t]
// Then ALL waves run the proven phase2 consumer loop (bit-identical numerics),
// reading PN masks from LDS. No producer/consumer concurrency -> race-free.
__global__ __launch_bounds__(TPB)
void snn_all(const float* __restrict__ or_input,   // [B,21]
             const float* __restrict__ or_gains,   // [21]
             const float* __restrict__ mapping,    // [21,42]
             const float* __restrict__ orn_to_pn,  // [42,42]
             const float* __restrict__ orn_to_ln,  // [42,56]
             const float* __restrict__ ln_to_pn,   // [56,42]
             const float* __restrict__ pn_to_kc,   // [42,2000]
             const float* __restrict__ kc_to_apl,  // [2000,1]
             const float* __restrict__ apl_to_kc,  // [1,2000]
             const float* __restrict__ dec_w,      // [2000,34]
             const float* __restrict__ dec_b,      // [34]
             float* __restrict__ out)              // [B,34]
{
    __shared__ ulonglong2 sAB[NSTEPS];          // {mOrn, mLn} per step (wave-0 private)
    __shared__ unsigned long long sPN[NSTEPS];  // PN masks (read-only in time loop)
    __shared__ float sRed[2][4];                // APL partials double buffer
    __shared__ float sRed2[4 * NOD];            // epilogue reduction

    const int tid  = threadIdx.x;
    const int lane = tid & 63;
    const int wid  = tid >> 6;
    const int b    = blockIdx.x;

    // ================= wave 0: small-net trajectory (sequential stages) =================
    if (wid == 0) {
        // ---- S1: ORN + LN (identical op order to proven phase1a) ----
        const int jl = lane < NLN ? lane : 0;
        float wOl[NORN];
#pragma unroll
        for (int o = 0; o < NORN; ++o) wOl[o] = orn_to_ln[o * NLN + jl];

        float spg = 0.f;
        if (lane < NOR) spg = log1pf(expf(or_gains[lane]));  // softplus

        float drive = 0.f;
        {
            const float* x = or_input + (long)b * NOR;
            const int jo = lane < NORN ? lane : 0;
#pragma unroll
            for (int i = 0; i < NOR; ++i) {
                float g = __shfl(spg, i);
                drive += x[i] * g * mapping[i * NORN + jo];
            }
            drive *= ISCALE;
        }

        float v_orn = 0.f, v_ln = 0.f;
        for (int t = 0; t < NSTEPS; ++t) {
            bool so = false;
            if (lane < NORN) {
                v_orn = ALPHA * v_orn + drive;
                so = (v_orn - VTH) > 0.f;
                if (so) v_orn = 0.f;
            }
            const unsigned long long mOrn = __ballot(so);
            const unsigned int mo_lo = (unsigned int)mOrn;
            const unsigned int mo_hi = (unsigned int)(mOrn >> 32);

            float aln = 0.f;
#pragma unroll
            for (int o = 0; o < 32; ++o) aln += (float)((mo_lo >> o) & 1u) * wOl[o];
#pragma unroll
            for (int o = 32; o < NORN; ++o) aln += (float)((mo_hi >> (o - 32)) & 1u) * wOl[o];

            bool sl = false;
            if (lane < NLN) {
                v_ln = ALPHA * v_ln + aln;
                sl = (v_ln - VTH) > 0.f;
                if (sl) v_ln = 0.f;
            }
            const unsigned long long mLn = __ballot(sl);
            if (lane == 0) sAB[t] = make_ulonglong2(mOrn, mLn);
        }
        asm volatile("" ::: "memory");   // keep S2a loads below (wOl now dead)

        // ---- S2a: PN excitation per step (identical op order to phase1b) ----
        const int jp = lane < NPN ? lane : 0;
        float wOp[NORN];
#pragma unroll
        for (int o = 0; o < NORN; ++o) wOp[o] = orn_to_pn[o * NPN + jp];

        float apn[NSTEPS];
#pragma unroll
        for (int t = 0; t < NSTEPS; ++t) {
            const unsigned long long mo = sAB[t].x;
            const unsigned int lo = (unsigned int)mo;
            const unsigned int hi = (unsigned int)(mo >> 32);
            float a = 0.f;
#pragma unroll
            for (int o = 0; o < 32; ++o) a += (float)((lo >> o) & 1u) * wOp[o];
#pragma unroll
            for (int o = 32; o < NORN; ++o) a += (float)((hi >> (o - 32)) & 1u) * wOp[o];
            apn[t] = a;
        }
        asm volatile("" ::: "memory");   // keep S2b loads below (wOp now dead)

        // ---- S2b: PN recurrence -> sPN ----
        float wLp[NLN];
#pragma unroll
        for (int l = 0; l < NLN; ++l) wLp[l] = ln_to_pn[l * NPN + jp];

        float v_pn = 0.f;
#pragma unroll
        for (int t = 0; t < NSTEPS; ++t) {
            const unsigned long long ml = sAB[t].y;
            const unsigned int lo = (unsigned int)ml;
            const unsigned int hi = (unsigned int)(ml >> 32);
            float h = 0.f;
#pragma unroll
            for (int l = 0; l < 32; ++l) h += (float)((lo >> l) & 1u) * wLp[l];
#pragma unroll
            for (int l = 32; l < NLN; ++l) h += (float)((hi >> (l - 32)) & 1u) * wLp[l];

            bool sp = false;
            if (lane < NPN) {
                v_pn = ALPHA * v_pn + apn[t] - h;   // (alpha*v + apn) - h, same as phase1b
                sp = (v_pn - VTH) > 0.f;
                if (sp) v_pn = 0.f;
            }
            const unsigned long long mPn = __ballot(sp);
            if (lane == 0) sPN[t] = mPn;
        }
    }

    // ================= all waves: consumer init (proven phase2 prologue) =================
    const int  kbase = tid * KPER;
    const bool act   = (tid < 250);
    float vd[KPER], va[KPER], cnt[KPER], wa2k[KPER], wk2a[KPER];
#pragma unroll
    for (int j = 0; j < KPER; ++j) { vd[j] = 0.f; va[j] = 0.f; cnt[j] = 0.f; }
    {
        const float4* a4 = (const float4*)(apl_to_kc + (act ? kbase : 0));
        const float4* k4 = (const float4*)(kc_to_apl + (act ? kbase : 0));
        float4 a0 = a4[0], a1 = a4[1], k0 = k4[0], k1 = k4[1];
        const float g = act ? 1.f : 0.f;
        wa2k[0] = g * a0.x; wa2k[1] = g * a0.y; wa2k[2] = g * a0.z; wa2k[3] = g * a0.w;
        wa2k[4] = g * a1.x; wa2k[5] = g * a1.y; wa2k[6] = g * a1.z; wa2k[7] = g * a1.w;
        wk2a[0] = g * k0.x; wk2a[1] = g * k0.y; wk2a[2] = g * k0.z; wk2a[3] = g * k0.w;
        wk2a[4] = g * k1.x; wk2a[5] = g * k1.y; wk2a[6] = g * k1.z; wk2a[7] = g * k1.w;
    }
    if (tid < 8) sRed[tid >> 2][tid & 3] = 0.f;   // zero both buffers
    __syncthreads();   // sPN + sRed zeros visible; wave-0 prologue complete

    // ================= proven consumer time loop: 1 barrier/step =================
    for (int t = 0; t < NSTEPS; ++t) {
        const float* rp = sRed[(t + 1) & 1];
        const float apl = fmaxf(rp[0] + rp[1] + rp[2] + rp[3], 0.f);

#pragma unroll
        for (int j = 0; j < KPER; ++j) vd[j] = ALPHA * vd[j] - apl * wa2k[j];

        // gather over spiking PNs: 2 rows/batch, 4 float4 loads in flight
        unsigned long long m = sPN[t];
        while (m) {
            const int p0 = __builtin_ctzll(m); m &= m - 1;
            int p1 = p0; float f1 = 0.f;
            if (m) { p1 = __builtin_ctzll(m); m &= m - 1; f1 = 1.f; }
            if (act) {
                const float4* w0 = (const float4*)(pn_to_kc + (long)p0 * NKC + kbase);
                const float4* w1 = (const float4*)(pn_to_kc + (long)p1 * NKC + kbase);
                float4 a0 = w0[0], a1 = w0[1];
                float4 b0 = w1[0], b1 = w1[1];
                vd[0] += a0.x; vd[1] += a0.y; vd[2] += a0.z; vd[3] += a0.w;
                vd[4] += a1.x; vd[5] += a1.y; vd[6] += a1.z; vd[7] += a1.w;
                vd[0] += f1 * b0.x; vd[1] += f1 * b0.y; vd[2] += f1 * b0.z; vd[3] += f1 * b0.w;
                vd[4] += f1 * b1.x; vd[5] += f1 * b1.y; vd[6] += f1 * b1.z; vd[7] += f1 * b1.w;
            }
        }

        float aplp = 0.f;
#pragma unroll
        for (int j = 0; j < KPER; ++j) {
            va[j] = ALPHA * va[j] + GSOMA * (vd[j] - va[j]);
            float s = (va[j] - VTH) > 0.f ? 1.f : 0.f;
            va[j] *= (1.f - s);
            cnt[j] += s;
            aplp += s * wk2a[j];
        }
        for (int off = 32; off > 0; off >>= 1) aplp += __shfl_xor(aplp, off, 64);
        if (lane == 0) sRed[t & 1][wid] = aplp;
        __syncthreads();
    }

    // ================= proven epilogue =================
    float acc[NOD];
#pragma unroll
    for (int o = 0; o < NOD; ++o) acc[o] = 0.f;
    if (act) {
#pragma unroll
        for (int j = 0; j < KPER; ++j) {
            float r = cnt[j] / 20.0f;
            if (r != 0.f) {                      // KC sparsity: skip silent KCs
                const float* wr = dec_w + (long)(kbase + j) * NOD;
#pragma unroll
                for (int o = 0; o < NOD; ++o) acc[o] += r * wr[o];
            }
        }
    }
#pragma unroll
    for (int o = 0; o < NOD; ++o) {
        float v = acc[o];
        for (int off = 32; off > 0; off >>= 1) v += __shfl_xor(v, off, 64);
        if (lane == 0) sRed2[wid * NOD + o] = v;
    }
    __syncthreads();
    if (tid < NOD) {
        float v = sRed2[tid] + sRed2[NOD + tid] + sRed2[2 * NOD + tid] +
                  sRed2[3 * NOD + tid] + dec_b[tid];
        out[(long)b * NOD + tid] = v;
    }
}

extern "C" void kernel_launch(void* const* d_in, const int* in_sizes, int n_in,
                              void* d_out, int out_size, void* d_ws, size_t ws_size,
                              hipStream_t stream) {
    (void)n_in; (void)out_size; (void)d_ws; (void)ws_size;
    const float* or_input  = (const float*)d_in[0];
    const float* or_gains  = (const float*)d_in[1];
    const float* mapping   = (const float*)d_in[2];
    const float* orn_to_pn = (const float*)d_in[3];
    const float* orn_to_ln = (const float*)d_in[4];
    const float* ln_to_pn  = (const float*)d_in[5];
    const float* pn_to_kc  = (const float*)d_in[6];
    const float* kc_to_apl = (const float*)d_in[7];
    const float* apl_to_kc = (const float*)d_in[8];
    const float* dec_w     = (const float*)d_in[9];
    const float* dec_b     = (const float*)d_in[10];
    float* out = (float*)d_out;

    const int batch = in_sizes[0] / NOR;  // 4096
    hipLaunchKernelGGL(snn_all, dim3(batch), dim3(TPB), 0, stream,
                       or_input, or_gains, mapping, orn_to_pn, orn_to_ln,
                       ln_to_pn, pn_to_kc, kc_to_apl, apl_to_kc, dec_w, dec_b, out);
}

// Round 12
// 252.243 us; speedup vs baseline: 1.0067x; 1.0067x over previous
//
#include <hip/hip_runtime.h>

#define NSTEPS 20
#define ALPHA  0.9f
#define VTH    1.0f
#define GSOMA  0.3f
#define ISCALE 0.5f

#define NOR  21
#define NORN 42
#define NLN  56
#define NPN  42
#define NKC  2000
#define NOD  34

#define TPB  256
#define KPER 8   // KCs per consumer thread: 250 * 8 = 2000
#define RPB  2   // batch rows per block

// One block = RPB batch rows.
// Prologue: wave w (w<RPB) computes row (b*RPB+w)'s full small-net trajectory
// with the R11-proven sequential register-light stages (S1 ORN+LN, S2a PN-exc,
// S2b PN recurrence), masks in per-wave-private LDS. No cross-wave access.
// Main loop: all 4 waves run the proven phase2 consumer numerics for BOTH rows,
// iterating the UNION of the two PN masks so each pn_to_kc load serves 2 rows
// (f in {0,1} multiplies are exact; +0.0 adds exact since vd is never -0.0).
__global__ __launch_bounds__(TPB)
void snn_all2(const float* __restrict__ or_input,   // [B,21]
              const float* __restrict__ or_gains,   // [21]
              const float* __restrict__ mapping,    // [21,42]
              const float* __restrict__ orn_to_pn,  // [42,42]
              const float* __restrict__ orn_to_ln,  // [42,56]
              const float* __restrict__ ln_to_pn,   // [56,42]
              const float* __restrict__ pn_to_kc,   // [42,2000]
              const float* __restrict__ kc_to_apl,  // [2000,1]
              const float* __restrict__ apl_to_kc,  // [1,2000]
              const float* __restrict__ dec_w,      // [2000,34]
              const float* __restrict__ dec_b,      // [34]
              float* __restrict__ out,              // [B,34]
              int batch)
{
    __shared__ ulonglong2 sAB[RPB][NSTEPS];          // per-prologue-wave scratch
    __shared__ unsigned long long sPN[RPB][NSTEPS];  // PN masks per row
    __shared__ float sRed[RPB][2][4];                // APL partials, double-buffered
    __shared__ float sRed2[4 * NOD];                 // epilogue reduction

    const int tid  = threadIdx.x;
    const int lane = tid & 63;
    const int wid  = tid >> 6;
    const int b    = blockIdx.x;
    const int row0 = b * RPB;

    // ================= prologue: waves 0..RPB-1, one row each =================
    if (wid < RPB && (row0 + wid) < batch) {
        const int row = row0 + wid;

        // ---- S1: ORN + LN (identical op order to proven phase1a) ----
        const int jl = lane < NLN ? lane : 0;
        float wOl[NORN];
#pragma unroll
        for (int o = 0; o < NORN; ++o) wOl[o] = orn_to_ln[o * NLN + jl];

        float spg = 0.f;
        if (lane < NOR) spg = log1pf(expf(or_gains[lane]));  // softplus

        float drive = 0.f;
        {
            const float* x = or_input + (long)row * NOR;
            const int jo = lane < NORN ? lane : 0;
#pragma unroll
            for (int i = 0; i < NOR; ++i) {
                float g = __shfl(spg, i);
                drive += x[i] * g * mapping[i * NORN + jo];
            }
            drive *= ISCALE;
        }

        float v_orn = 0.f, v_ln = 0.f;
        for (int t = 0; t < NSTEPS; ++t) {
            bool so = false;
            if (lane < NORN) {
                v_orn = ALPHA * v_orn + drive;
                so = (v_orn - VTH) > 0.f;
                if (so) v_orn = 0.f;
            }
            const unsigned long long mOrn = __ballot(so);
            const unsigned int mo_lo = (unsigned int)mOrn;
            const unsigned int mo_hi = (unsigned int)(mOrn >> 32);

            float aln = 0.f;
#pragma unroll
            for (int o = 0; o < 32; ++o) aln += (float)((mo_lo >> o) & 1u) * wOl[o];
#pragma unroll
            for (int o = 32; o < NORN; ++o) aln += (float)((mo_hi >> (o - 32)) & 1u) * wOl[o];

            bool sl = false;
            if (lane < NLN) {
                v_ln = ALPHA * v_ln + aln;
                sl = (v_ln - VTH) > 0.f;
                if (sl) v_ln = 0.f;
            }
            const unsigned long long mLn = __ballot(sl);
            if (lane == 0) sAB[wid][t] = make_ulonglong2(mOrn, mLn);
        }
        asm volatile("" ::: "memory");

        // ---- S2a: PN excitation per step ----
        const int jp = lane < NPN ? lane : 0;
        float wOp[NORN];
#pragma unroll
        for (int o = 0; o < NORN; ++o) wOp[o] = orn_to_pn[o * NPN + jp];

        float apn[NSTEPS];
#pragma unroll
        for (int t = 0; t < NSTEPS; ++t) {
            const unsigned long long mo = sAB[wid][t].x;
            const unsigned int lo = (unsigned int)mo;
            const unsigned int hi = (unsigned int)(mo >> 32);
            float a = 0.f;
#pragma unroll
            for (int o = 0; o < 32; ++o) a += (float)((lo >> o) & 1u) * wOp[o];
#pragma unroll
            for (int o = 32; o < NORN; ++o) a += (float)((hi >> (o - 32)) & 1u) * wOp[o];
            apn[t] = a;
        }
        asm volatile("" ::: "memory");

        // ---- S2b: PN recurrence -> sPN ----
        float wLp[NLN];
#pragma unroll
        for (int l = 0; l < NLN; ++l) wLp[l] = ln_to_pn[l * NPN + jp];

        float v_pn = 0.f;
#pragma unroll
        for (int t = 0; t < NSTEPS; ++t) {
            const unsigned long long ml = sAB[wid][t].y;
            const unsigned int lo = (unsigned int)ml;
            const unsigned int hi = (unsigned int)(ml >> 32);
            float h = 0.f;
#pragma unroll
            for (int l = 0; l < 32; ++l) h += (float)((lo >> l) & 1u) * wLp[l];
#pragma unroll
            for (int l = 32; l < NLN; ++l) h += (float)((hi >> (l - 32)) & 1u) * wLp[l];

            bool sp = false;
            if (lane < NPN) {
                v_pn = ALPHA * v_pn + apn[t] - h;
                sp = (v_pn - VTH) > 0.f;
                if (sp) v_pn = 0.f;
            }
            const unsigned long long mPn = __ballot(sp);
            if (lane == 0) sPN[wid][t] = mPn;
        }
    } else if (wid < RPB) {
        // row out of range: publish empty masks
        if (lane < NSTEPS) sPN[wid][lane] = 0ULL;
    }

    // ================= consumer init (proven phase2 prologue, x2 rows) =================
    const int  kbase = tid * KPER;
    const bool act   = (tid < 250);
    float vd0[KPER], va0[KPER], cnt0[KPER];
    float vd1[KPER], va1[KPER], cnt1[KPER];
    float wa2k[KPER], wk2a[KPER];
#pragma unroll
    for (int j = 0; j < KPER; ++j) {
        vd0[j] = 0.f; va0[j] = 0.f; cnt0[j] = 0.f;
        vd1[j] = 0.f; va1[j] = 0.f; cnt1[j] = 0.f;
    }
    {
        const float4* a4 = (const float4*)(apl_to_kc + (act ? kbase : 0));
        const float4* k4 = (const float4*)(kc_to_apl + (act ? kbase : 0));
        float4 a0 = a4[0], a1 = a4[1], k0 = k4[0], k1 = k4[1];
        const float g = act ? 1.f : 0.f;
        wa2k[0] = g * a0.x; wa2k[1] = g * a0.y; wa2k[2] = g * a0.z; wa2k[3] = g * a0.w;
        wa2k[4] = g * a1.x; wa2k[5] = g * a1.y; wa2k[6] = g * a1.z; wa2k[7] = g * a1.w;
        wk2a[0] = g * k0.x; wk2a[1] = g * k0.y; wk2a[2] = g * k0.z; wk2a[3] = g * k0.w;
        wk2a[4] = g * k1.x; wk2a[5] = g * k1.y; wk2a[6] = g * k1.z; wk2a[7] = g * k1.w;
    }
    if (tid < RPB * 2 * 4) ((float*)sRed)[tid] = 0.f;   // zero all buffers
    __syncthreads();   // masks + zeros visible; prologue complete

    // ================= consumer time loop: 1 barrier/step =================
    for (int t = 0; t < NSTEPS; ++t) {
        const float* rp0 = sRed[0][(t + 1) & 1];
        const float* rp1 = sRed[1][(t + 1) & 1];
        const float apl0 = fmaxf(rp0[0] + rp0[1] + rp0[2] + rp0[3], 0.f);
        const float apl1 = fmaxf(rp1[0] + rp1[1] + rp1[2] + rp1[3], 0.f);

#pragma unroll
        for (int j = 0; j < KPER; ++j) {
            vd0[j] = ALPHA * vd0[j] - apl0 * wa2k[j];
            vd1[j] = ALPHA * vd1[j] - apl1 * wa2k[j];
        }

        // gather over the UNION of both rows' spiking PNs, 2 bits per batch
        const unsigned long long m0 = sPN[0][t];
        const unsigned long long m1 = sPN[1][t];
        unsigned long long mu = m0 | m1;
        while (mu) {
            const int p0 = __builtin_ctzll(mu); mu &= mu - 1;
            int p1 = p0; float g1 = 0.f;
            if (mu) { p1 = __builtin_ctzll(mu); mu &= mu - 1; g1 = 1.f; }
            if (act) {
                const float f00 = (float)((m0 >> p0) & 1ULL);  // row0, bit p0
                const float f01 = g1 * (float)((m0 >> p1) & 1ULL);
                const float f10 = (float)((m1 >> p0) & 1ULL);  // row1
                const float f11 = g1 * (float)((m1 >> p1) & 1ULL);
                const float4* w0 = (const float4*)(pn_to_kc + (long)p0 * NKC + kbase);
                const float4* w1 = (const float4*)(pn_to_kc + (long)p1 * NKC + kbase);
                float4 a0 = w0[0], a1 = w0[1];
                float4 b0 = w1[0], b1 = w1[1];
                // ascending order per row; f in {0,1} -> exact terms / exact +0.0
                vd0[0] += f00 * a0.x; vd0[1] += f00 * a0.y; vd0[2] += f00 * a0.z; vd0[3] += f00 * a0.w;
                vd0[4] += f00 * a1.x; vd0[5] += f00 * a1.y; vd0[6] += f00 * a1.z; vd0[7] += f00 * a1.w;
                vd0[0] += f01 * b0.x; vd0[1] += f01 * b0.y; vd0[2] += f01 * b0.z; vd0[3] += f01 * b0.w;
                vd0[4] += f01 * b1.x; vd0[5] += f01 * b1.y; vd0[6] += f01 * b1.z; vd0[7] += f01 * b1.w;
                vd1[0] += f10 * a0.x; vd1[1] += f10 * a0.y; vd1[2] += f10 * a0.z; vd1[3] += f10 * a0.w;
                vd1[4] += f10 * a1.x; vd1[5] += f10 * a1.y; vd1[6] += f10 * a1.z; vd1[7] += f10 * a1.w;
                vd1[0] += f11 * b0.x; vd1[1] += f11 * b0.y; vd1[2] += f11 * b0.z; vd1[3] += f11 * b0.w;
                vd1[4] += f11 * b1.x; vd1[5] += f11 * b1.y; vd1[6] += f11 * b1.z; vd1[7] += f11 * b1.w;
            }
        }

        float aplp0 = 0.f, aplp1 = 0.f;
#pragma unroll
        for (int j = 0; j < KPER; ++j) {
            va0[j] = ALPHA * va0[j] + GSOMA * (vd0[j] - va0[j]);
            float s0 = (va0[j] - VTH) > 0.f ? 1.f : 0.f;
            va0[j] *= (1.f - s0);
            cnt0[j] += s0;
            aplp0 += s0 * wk2a[j];
            va1[j] = ALPHA * va1[j] + GSOMA * (vd1[j] - va1[j]);
            float s1 = (va1[j] - VTH) > 0.f ? 1.f : 0.f;
            va1[j] *= (1.f - s1);
            cnt1[j] += s1;
            aplp1 += s1 * wk2a[j];
        }
        for (int off = 32; off > 0; off >>= 1) {
            aplp0 += __shfl_xor(aplp0, off, 64);
            aplp1 += __shfl_xor(aplp1, off, 64);
        }
        if (lane == 0) {
            sRed[0][t & 1][wid] = aplp0;
            sRed[1][t & 1][wid] = aplp1;
        }
        __syncthreads();
    }

    // ================= epilogue: two rows, proven numerics =================
#define EPILOG(CNT, ROW)                                                        \
    do {                                                                        \
        float acc[NOD];                                                         \
        _Pragma("unroll")                                                       \
        for (int o = 0; o < NOD; ++o) acc[o] = 0.f;                             \
        if (act) {                                                              \
            _Pragma("unroll")                                                   \
            for (int j = 0; j < KPER; ++j) {                                    \
                float r = CNT[j] / 20.0f;                                       \
                if (r != 0.f) {                                                 \
                    const float* wr = dec_w + (long)(kbase + j) * NOD;          \
                    _Pragma("unroll")                                           \
                    for (int o = 0; o < NOD; ++o) acc[o] += r * wr[o];          \
                }                                                               \
            }                                                                   \
        }                                                                       \
        _Pragma("unroll")                                                       \
        for (int o = 0; o < NOD; ++o) {                                         \
            float v = acc[o];                                                   \
            for (int off = 32; off > 0; off >>= 1) v += __shfl_xor(v, off, 64); \
            if (lane == 0) sRed2[wid * NOD + o] = v;                            \
        }                                                                       \
        __syncthreads();                                                        \
        if (tid < NOD && (ROW) < batch) {                                       \
            float v = sRed2[tid] + sRed2[NOD + tid] + sRed2[2 * NOD + tid] +    \
                      sRed2[3 * NOD + tid] + dec_b[tid];                        \
            out[(long)(ROW) * NOD + tid] = v;                                   \
        }                                                                       \
        __syncthreads();                                                        \
    } while (0)

    EPILOG(cnt0, row0);
    EPILOG(cnt1, row0 + 1);
#undef EPILOG
}

extern "C" void kernel_launch(void* const* d_in, const int* in_sizes, int n_in,
                              void* d_out, int out_size, void* d_ws, size_t ws_size,
                              hipStream_t stream) {
    (void)n_in; (void)out_size; (void)d_ws; (void)ws_size;
    const float* or_input  = (const float*)d_in[0];
    const float* or_gains  = (const float*)d_in[1];
    const float* mapping   = (const float*)d_in[2];
    const float* orn_to_pn = (const float*)d_in[3];
    const float* orn_to_ln = (const float*)d_in[4];
    const float* ln_to_pn  = (const float*)d_in[5];
    const float* pn_to_kc  = (const float*)d_in[6];
    const float* kc_to_apl = (const float*)d_in[7];
    const float* apl_to_kc = (const float*)d_in[8];
    const float* dec_w     = (const float*)d_in[9];
    const float* dec_b     = (const float*)d_in[10];
    float* out = (float*)d_out;

    const int batch = in_sizes[0] / NOR;  // 4096
    hipLaunchKernelGGL(snn_all2, dim3((batch + RPB - 1) / RPB), dim3(TPB), 0, stream,
                       or_input, or_gains, mapping, orn_to_pn, orn_to_ln,
                       ln_to_pn, pn_to_kc, kc_to_apl, apl_to_kc, dec_w, dec_b, out, batch);
}

// Round 13
// 213.214 us; speedup vs baseline: 1.1910x; 1.1831x over previous
//
#include <hip/hip_runtime.h>

#define NSTEPS 20
#define ALPHA  0.9f
#define VTH    1.0f
#define GSOMA  0.3f
#define ISCALE 0.5f

#define NOR  21
#define NORN 42
#define NLN  56
#define NPN  42
#define NKC  2000
#define NOD  34

#define TPB  256
#define KPER 8   // KCs per consumer thread: 250 * 8 = 2000

// ============ Phase 1 (merged): small net -> PN spike masks ============
// One wave per row, 4 rows per 256-thr block, zero barriers.
// R11-proven sequential register-light stages (absmax 0.0):
//   S1 : ORN+LN recurrence  (wOl[42] regs)         -> sAB[wid][t]
//   S2a: PN excitation/step (wOp[42] regs)         -> apn[20] regs
//   S2b: PN recurrence      (wLp[56]+apn[20] regs) -> gPN[row][t]
// Per-wave-private LDS scratch; no cross-wave access anywhere.
__global__ __launch_bounds__(TPB)
void phase1_seq(const float* __restrict__ or_input,   // [B,21]
                const float* __restrict__ or_gains,   // [21]
                const float* __restrict__ mapping,    // [21,42]
                const float* __restrict__ orn_to_pn,  // [42,42]
                const float* __restrict__ orn_to_ln,  // [42,56]
                const float* __restrict__ ln_to_pn,   // [56,42]
                unsigned long long* __restrict__ gPN, // [B,20]
                int batch)
{
    __shared__ ulonglong2 sAB[4][NSTEPS];   // per-wave private scratch

    const int tid  = threadIdx.x;
    const int lane = tid & 63;
    const int wid  = tid >> 6;
    const int row  = blockIdx.x * 4 + wid;
    if (row >= batch) return;   // whole wave exits; no barriers below

    // ---- S1: ORN + LN (identical op order to proven phase1a) ----
    const int jl = lane < NLN ? lane : 0;
    float wOl[NORN];
#pragma unroll
    for (int o = 0; o < NORN; ++o) wOl[o] = orn_to_ln[o * NLN + jl];

    float spg = 0.f;
    if (lane < NOR) spg = log1pf(expf(or_gains[lane]));  // softplus

    float drive = 0.f;
    {
        const float* x = or_input + (long)row * NOR;
        const int jo = lane < NORN ? lane : 0;
#pragma unroll
        for (int i = 0; i < NOR; ++i) {
            float g = __shfl(spg, i);
            drive += x[i] * g * mapping[i * NORN + jo];
        }
        drive *= ISCALE;
    }

    float v_orn = 0.f, v_ln = 0.f;
    for (int t = 0; t < NSTEPS; ++t) {
        bool so = false;
        if (lane < NORN) {
            v_orn = ALPHA * v_orn + drive;
            so = (v_orn - VTH) > 0.f;
            if (so) v_orn = 0.f;
        }
        const unsigned long long mOrn = __ballot(so);
        const unsigned int mo_lo = (unsigned int)mOrn;
        const unsigned int mo_hi = (unsigned int)(mOrn >> 32);

        float aln = 0.f;
#pragma unroll
        for (int o = 0; o < 32; ++o) aln += (float)((mo_lo >> o) & 1u) * wOl[o];
#pragma unroll
        for (int o = 32; o < NORN; ++o) aln += (float)((mo_hi >> (o - 32)) & 1u) * wOl[o];

        bool sl = false;
        if (lane < NLN) {
            v_ln = ALPHA * v_ln + aln;
            sl = (v_ln - VTH) > 0.f;
            if (sl) v_ln = 0.f;
        }
        const unsigned long long mLn = __ballot(sl);
        if (lane == 0) sAB[wid][t] = make_ulonglong2(mOrn, mLn);
    }
    asm volatile("" ::: "memory");   // keep S2a loads below (wOl now dead)

    // ---- S2a: PN excitation per step (identical op order to phase1b) ----
    const int jp = lane < NPN ? lane : 0;
    float wOp[NORN];
#pragma unroll
    for (int o = 0; o < NORN; ++o) wOp[o] = orn_to_pn[o * NPN + jp];

    float apn[NSTEPS];
#pragma unroll
    for (int t = 0; t < NSTEPS; ++t) {
        const unsigned long long mo = sAB[wid][t].x;
        const unsigned int lo = (unsigned int)mo;
        const unsigned int hi = (unsigned int)(mo >> 32);
        float a = 0.f;
#pragma unroll
        for (int o = 0; o < 32; ++o) a += (float)((lo >> o) & 1u) * wOp[o];
#pragma unroll
        for (int o = 32; o < NORN; ++o) a += (float)((hi >> (o - 32)) & 1u) * wOp[o];
        apn[t] = a;
    }
    asm volatile("" ::: "memory");   // keep S2b loads below (wOp now dead)

    // ---- S2b: PN recurrence -> gPN ----
    float wLp[NLN];
#pragma unroll
    for (int l = 0; l < NLN; ++l) wLp[l] = ln_to_pn[l * NPN + jp];

    unsigned long long* outm = gPN + (long)row * NSTEPS;
    float v_pn = 0.f;
#pragma unroll
    for (int t = 0; t < NSTEPS; ++t) {
        const unsigned long long ml = sAB[wid][t].y;
        const unsigned int lo = (unsigned int)ml;
        const unsigned int hi = (unsigned int)(ml >> 32);
        float h = 0.f;
#pragma unroll
        for (int l = 0; l < 32; ++l) h += (float)((lo >> l) & 1u) * wLp[l];
#pragma unroll
        for (int l = 32; l < NLN; ++l) h += (float)((hi >> (l - 32)) & 1u) * wLp[l];

        bool sp = false;
        if (lane < NPN) {
            v_pn = ALPHA * v_pn + apn[t] - h;
            sp = (v_pn - VTH) > 0.f;
            if (sp) v_pn = 0.f;
        }
        const unsigned long long mPn = __ballot(sp);
        if (lane == 0) outm[t] = mPn;
    }
}

// ===================== Phase 2: KC two-compartment + APL + logits =====================
// (R5/R9 version, proven 95 us / absmax 0.0 — unchanged)
__global__ __launch_bounds__(TPB)
void phase2_kernel(const unsigned long long* __restrict__ g_masks, // [B,20]
                   const float* __restrict__ pn_to_kc,  // [42,2000]
                   const float* __restrict__ kc_to_apl, // [2000,1]
                   const float* __restrict__ apl_to_kc, // [1,2000]
                   const float* __restrict__ dec_w,     // [2000,34]
                   const float* __restrict__ dec_b,     // [34]
                   float* __restrict__ out)             // [B,34]
{
    __shared__ float sRed[2][4];
    __shared__ float sRed2[4 * NOD];

    const int tid  = threadIdx.x;
    const int lane = tid & 63;
    const int wid  = tid >> 6;
    const int b    = blockIdx.x;

    const int  kbase = tid * KPER;
    const bool act   = (kbase < NKC);   // tid < 250
    float vd[KPER], va[KPER], cnt[KPER], wa2k[KPER], wk2a[KPER];
#pragma unroll
    for (int j = 0; j < KPER; ++j) { vd[j] = 0.f; va[j] = 0.f; cnt[j] = 0.f; }
    {
        const float4* a4 = (const float4*)(apl_to_kc + (act ? kbase : 0));
        const float4* k4 = (const float4*)(kc_to_apl + (act ? kbase : 0));
        float4 a0 = a4[0], a1 = a4[1], k0 = k4[0], k1 = k4[1];
        const float g = act ? 1.f : 0.f;
        wa2k[0] = g * a0.x; wa2k[1] = g * a0.y; wa2k[2] = g * a0.z; wa2k[3] = g * a0.w;
        wa2k[4] = g * a1.x; wa2k[5] = g * a1.y; wa2k[6] = g * a1.z; wa2k[7] = g * a1.w;
        wk2a[0] = g * k0.x; wk2a[1] = g * k0.y; wk2a[2] = g * k0.z; wk2a[3] = g * k0.w;
        wk2a[4] = g * k1.x; wk2a[5] = g * k1.y; wk2a[6] = g * k1.z; wk2a[7] = g * k1.w;
    }
    if (tid < 8) sRed[tid >> 2][tid & 3] = 0.f;   // zero both buffers
    __syncthreads();

    const unsigned long long* gm = g_masks + (long)b * NSTEPS;

    for (int t = 0; t < NSTEPS; ++t) {
        const float* rp = sRed[(t + 1) & 1];
        const float apl = fmaxf(rp[0] + rp[1] + rp[2] + rp[3], 0.f);

#pragma unroll
        for (int j = 0; j < KPER; ++j) vd[j] = ALPHA * vd[j] - apl * wa2k[j];

        unsigned long long m = gm[t];   // wave-uniform scalar load
        while (m) {
            const int p0 = __builtin_ctzll(m); m &= m - 1;
            int p1 = p0; float f1 = 0.f;
            if (m) { p1 = __builtin_ctzll(m); m &= m - 1; f1 = 1.f; }
            if (act) {
                const float4* w0 = (const float4*)(pn_to_kc + (long)p0 * NKC + kbase);
                const float4* w1 = (const float4*)(pn_to_kc + (long)p1 * NKC + kbase);
                float4 a0 = w0[0], a1 = w0[1];
                float4 b0 = w1[0], b1 = w1[1];
                vd[0] += a0.x; vd[1] += a0.y; vd[2] += a0.z; vd[3] += a0.w;
                vd[4] += a1.x; vd[5] += a1.y; vd[6] += a1.z; vd[7] += a1.w;
                vd[0] += f1 * b0.x; vd[1] += f1 * b0.y; vd[2] += f1 * b0.z; vd[3] += f1 * b0.w;
                vd[4] += f1 * b1.x; vd[5] += f1 * b1.y; vd[6] += f1 * b1.z; vd[7] += f1 * b1.w;
            }
        }

        float aplp = 0.f;
#pragma unroll
        for (int j = 0; j < KPER; ++j) {
            va[j] = ALPHA * va[j] + GSOMA * (vd[j] - va[j]);
            float s = (va[j] - VTH) > 0.f ? 1.f : 0.f;
            va[j] *= (1.f - s);
            cnt[j] += s;
            aplp += s * wk2a[j];
        }
        for (int off = 32; off > 0; off >>= 1) aplp += __shfl_xor(aplp, off, 64);
        if (lane == 0) sRed[t & 1][wid] = aplp;
        __syncthreads();
    }

    float acc[NOD];
#pragma unroll
    for (int o = 0; o < NOD; ++o) acc[o] = 0.f;
    if (act) {
#pragma unroll
        for (int j = 0; j < KPER; ++j) {
            float r = cnt[j] / 20.0f;
            if (r != 0.f) {
                const float* wr = dec_w + (long)(kbase + j) * NOD;
#pragma unroll
                for (int o = 0; o < NOD; ++o) acc[o] += r * wr[o];
            }
        }
    }
#pragma unroll
    for (int o = 0; o < NOD; ++o) {
        float v = acc[o];
        for (int off = 32; off > 0; off >>= 1) v += __shfl_xor(v, off, 64);
        if (lane == 0) sRed2[wid * NOD + o] = v;
    }
    __syncthreads();
    if (tid < NOD) {
        float v = sRed2[tid] + sRed2[NOD + tid] + sRed2[2 * NOD + tid] +
                  sRed2[3 * NOD + tid] + dec_b[tid];
        out[(long)b * NOD + tid] = v;
    }
}

// ===================== Fallback: round-1 fused kernel (proven) =====================
__global__ __launch_bounds__(TPB)
void snn_fused(const float* __restrict__ or_input, const float* __restrict__ or_gains,
               const float* __restrict__ mapping, const float* __restrict__ orn_to_pn,
               const float* __restrict__ orn_to_ln, const float* __restrict__ ln_to_pn,
               const float* __restrict__ pn_to_kc, const float* __restrict__ kc_to_apl,
               const float* __restrict__ apl_to_kc, const float* __restrict__ dec_w,
               const float* __restrict__ dec_b, float* __restrict__ out)
{
    __shared__ float sW_ol[NORN * NLN];
    __shared__ float sW_op[NORN * NPN];
    __shared__ float sW_lp[NLN * NPN];
    __shared__ float sDrive[NORN];
    __shared__ float sSpg[NOR];
    __shared__ float sOrn[NORN];
    __shared__ float sLn[NLN];
    __shared__ float sApl;
    __shared__ float sRed[4];
    __shared__ float sRed2[4 * NOD];
    __shared__ unsigned long long sMask;

    const int tid = threadIdx.x;
    const int b   = blockIdx.x;

    for (int i = tid; i < NORN * NLN; i += TPB) sW_ol[i] = orn_to_ln[i];
    for (int i = tid; i < NORN * NPN; i += TPB) sW_op[i] = orn_to_pn[i];
    for (int i = tid; i < NLN * NPN;  i += TPB) sW_lp[i] = ln_to_pn[i];
    if (tid < NOR) sSpg[tid] = log1pf(expf(or_gains[tid]));
    if (tid == 0)  sApl = 0.f;
    __syncthreads();

    if (tid < NORN) {
        const float* x = or_input + (long)b * NOR;
        float d = 0.f;
        for (int i = 0; i < NOR; ++i) d += x[i] * sSpg[i] * mapping[i * NORN + tid];
        sDrive[tid] = d * ISCALE;
    }

    const int  kbase = tid * KPER;
    const bool act   = (kbase < NKC);
    float vd[KPER], va[KPER], cnt[KPER], wa2k[KPER], wk2a[KPER];
#pragma unroll
    for (int j = 0; j < KPER; ++j) {
        vd[j] = 0.f; va[j] = 0.f; cnt[j] = 0.f;
        wa2k[j] = act ? apl_to_kc[kbase + j] : 0.f;
        wk2a[j] = act ? kc_to_apl[kbase + j] : 0.f;
    }
    float v_orn = 0.f, v_ln = 0.f, v_pn = 0.f, v_pn_exc = 0.f;
    __syncthreads();

    for (int t = 0; t < NSTEPS; ++t) {
        if (tid < NORN) {
            v_orn = ALPHA * v_orn + sDrive[tid];
            float s = (v_orn - VTH) > 0.f ? 1.f : 0.f;
            v_orn *= (1.f - s);
            sOrn[tid] = s;
        }
        __syncthreads();
        if (tid < NLN) {
            float a = 0.f;
            for (int o = 0; o < NORN; ++o) a += sOrn[o] * sW_ol[o * NLN + tid];
            v_ln = ALPHA * v_ln + a;
            float s = (v_ln - VTH) > 0.f ? 1.f : 0.f;
            v_ln *= (1.f - s);
            sLn[tid] = s;
        } else if (tid >= 64 && tid < 64 + NPN) {
            const int j = tid - 64;
            float a = 0.f;
            for (int o = 0; o < NORN; ++o) a += sOrn[o] * sW_op[o * NPN + j];
            v_pn_exc = a;
        }
        __syncthreads();
        if (tid >= 64 && tid < 64 + NPN) {
            const int j = tid - 64;
            float inh = 0.f;
            for (int l = 0; l < NLN; ++l) inh += sLn[l] * sW_lp[l * NPN + j];
            v_pn = ALPHA * v_pn + v_pn_exc - inh;
            bool s = (v_pn - VTH) > 0.f;
            if (s) v_pn = 0.f;
            unsigned long long bal = __ballot(s);
            if (tid == 64) sMask = bal;
        }
        __syncthreads();
        {
            const float apl = sApl;
#pragma unroll
            for (int j = 0; j < KPER; ++j) vd[j] = ALPHA * vd[j] - apl * wa2k[j];
            unsigned long long m = sMask;
            while (m) {
                const int p = __builtin_ctzll(m);
                m &= m - 1;
                if (act) {
                    const float4* w = (const float4*)(pn_to_kc + (long)p * NKC + kbase);
                    float4 w0 = w[0], w1 = w[1];
                    vd[0] += w0.x; vd[1] += w0.y; vd[2] += w0.z; vd[3] += w0.w;
                    vd[4] += w1.x; vd[5] += w1.y; vd[6] += w1.z; vd[7] += w1.w;
                }
            }
            float aplp = 0.f;
#pragma unroll
            for (int j = 0; j < KPER; ++j) {
                va[j] = ALPHA * va[j] + GSOMA * (vd[j] - va[j]);
                float s = (va[j] - VTH) > 0.f ? 1.f : 0.f;
                va[j] *= (1.f - s);
                cnt[j] += s;
                aplp += s * wk2a[j];
            }
            for (int off = 32; off > 0; off >>= 1) aplp += __shfl_xor(aplp, off, 64);
            if ((tid & 63) == 0) sRed[tid >> 6] = aplp;
        }
        __syncthreads();
        if (tid == 0) {
            float a = sRed[0] + sRed[1] + sRed[2] + sRed[3];
            sApl = fmaxf(a, 0.f);
        }
    }

    float acc[NOD];
#pragma unroll
    for (int o = 0; o < NOD; ++o) acc[o] = 0.f;
    if (act) {
#pragma unroll
        for (int j = 0; j < KPER; ++j) {
            float r = cnt[j] / 20.0f;
            if (r != 0.f) {
                const float* wr = dec_w + (long)(kbase + j) * NOD;
#pragma unroll
                for (int o = 0; o < NOD; ++o) acc[o] += r * wr[o];
            }
        }
    }
#pragma unroll
    for (int o = 0; o < NOD; ++o) {
        float v = acc[o];
        for (int off = 32; off > 0; off >>= 1) v += __shfl_xor(v, off, 64);
        if ((tid & 63) == 0) sRed2[(tid >> 6) * NOD + o] = v;
    }
    __syncthreads();
    if (tid < NOD) {
        float v = sRed2[tid] + sRed2[NOD + tid] + sRed2[2 * NOD + tid] +
                  sRed2[3 * NOD + tid] + dec_b[tid];
        out[(long)b * NOD + tid] = v;
    }
}

extern "C" void kernel_launch(void* const* d_in, const int* in_sizes, int n_in,
                              void* d_out, int out_size, void* d_ws, size_t ws_size,
                              hipStream_t stream) {
    (void)n_in; (void)out_size;
    const float* or_input  = (const float*)d_in[0];
    const float* or_gains  = (const float*)d_in[1];
    const float* mapping   = (const float*)d_in[2];
    const float* orn_to_pn = (const float*)d_in[3];
    const float* orn_to_ln = (const float*)d_in[4];
    const float* ln_to_pn  = (const float*)d_in[5];
    const float* pn_to_kc  = (const float*)d_in[6];
    const float* kc_to_apl = (const float*)d_in[7];
    const float* apl_to_kc = (const float*)d_in[8];
    const float* dec_w     = (const float*)d_in[9];
    const float* dec_b     = (const float*)d_in[10];
    float* out = (float*)d_out;

    const int batch = in_sizes[0] / NOR;  // 4096
    const size_t needPN = (size_t)batch * NSTEPS * sizeof(unsigned long long);  // 0.66 MB

    if (ws_size >= needPN) {
        unsigned long long* gPN = (unsigned long long*)d_ws;
        hipLaunchKernelGGL(phase1_seq, dim3((batch + 3) / 4), dim3(TPB), 0, stream,
                           or_input, or_gains, mapping, orn_to_pn, orn_to_ln, ln_to_pn,
                           gPN, batch);
        hipLaunchKernelGGL(phase2_kernel, dim3(batch), dim3(TPB), 0, stream,
                           gPN, pn_to_kc, kc_to_apl, apl_to_kc, dec_w, dec_b, out);
    } else {
        hipLaunchKernelGGL(snn_fused, dim3(batch), dim3(TPB), 0, stream,
                           or_input, or_gains, mapping, orn_to_pn, orn_to_ln,
                           ln_to_pn, pn_to_kc, kc_to_apl, apl_to_kc, dec_w, dec_b, out);
    }
}

// Round 14
// 209.351 us; speedup vs baseline: 1.2130x; 1.0185x over previous
//
#include <hip/hip_runtime.h>

#define NSTEPS 20
#define ALPHA  0.9f
#define VTH    1.0f
#define GSOMA  0.3f
#define ISCALE 0.5f

#define NOR  21
#define NORN 42
#define NLN  56
#define NPN  42
#define NKC  2000
#define NOD  34

#define TPB  256
#define KPER 8   // KCs per consumer thread: 250 * 8 = 2000

// ============ Phase 1a: ORN + LN dynamics -> {mOrn, mLn} per step ============
// One wave per row. Only wOl[42] in registers (~60 VGPR total, no spill).
// Zero LDS, zero barriers. (R9-proven: absmax 0.0, best total 210.7 us)
__global__ __launch_bounds__(64)
void phase1a(const float* __restrict__ or_input,   // [B,21]
             const float* __restrict__ or_gains,   // [21]
             const float* __restrict__ mapping,    // [21,42]
             const float* __restrict__ orn_to_ln,  // [42,56]
             ulonglong2* __restrict__ gAB,         // [B,20] {mOrn, mLn}
             int batch)
{
    const int lane = threadIdx.x;
    const int row  = blockIdx.x;
    if (row >= batch) return;

    const int jl = lane < NLN ? lane : 0;
    float wOl[NORN];
#pragma unroll
    for (int o = 0; o < NORN; ++o) wOl[o] = orn_to_ln[o * NLN + jl];

    float spg = 0.f;
    if (lane < NOR) spg = log1pf(expf(or_gains[lane]));  // softplus

    float drive = 0.f;
    {
        const float* x = or_input + (long)row * NOR;
        const int jo = lane < NORN ? lane : 0;
#pragma unroll
        for (int i = 0; i < NOR; ++i) {
            float g = __shfl(spg, i);
            drive += x[i] * g * mapping[i * NORN + jo];
        }
        drive *= ISCALE;
    }

    float v_orn = 0.f, v_ln = 0.f;
    ulonglong2* outm = gAB + (long)row * NSTEPS;

    for (int t = 0; t < NSTEPS; ++t) {
        // ORN LIF (lane = ORN index)
        bool so = false;
        if (lane < NORN) {
            v_orn = ALPHA * v_orn + drive;
            so = (v_orn - VTH) > 0.f;
            if (so) v_orn = 0.f;
        }
        const unsigned long long mOrn = __ballot(so);
        const unsigned int mo_lo = (unsigned int)mOrn;
        const unsigned int mo_hi = (unsigned int)(mOrn >> 32);

        // LN input: dense ascending-o; s in {0,1} via bit extract (exact)
        float aln = 0.f;
#pragma unroll
        for (int o = 0; o < 32; ++o) aln += (float)((mo_lo >> o) & 1u) * wOl[o];
#pragma unroll
        for (int o = 32; o < NORN; ++o) aln += (float)((mo_hi >> (o - 32)) & 1u) * wOl[o];

        bool sl = false;
        if (lane < NLN) {
            v_ln = ALPHA * v_ln + aln;
            sl = (v_ln - VTH) > 0.f;
            if (sl) v_ln = 0.f;
        }
        const unsigned long long mLn = __ballot(sl);
        if (lane == 0) outm[t] = make_ulonglong2(mOrn, mLn);
    }
}

// ============ Phase 1b: PN dynamics -> PN spike masks ============
// One wave per row. wOp[42]+wLp[56] = 98 weight regs + ~20 temps < 128: no spill.
__global__ __launch_bounds__(64)
void phase1b(const float* __restrict__ orn_to_pn,  // [42,42]
             const float* __restrict__ ln_to_pn,   // [56,42]
             const ulonglong2* __restrict__ gAB,   // [B,20]
             unsigned long long* __restrict__ gPN, // [B,20]
             int batch)
{
    const int lane = threadIdx.x;
    const int row  = blockIdx.x;
    if (row >= batch) return;

    const int jp = lane < NPN ? lane : 0;
    float wOp[NORN], wLp[NLN];
#pragma unroll
    for (int o = 0; o < NORN; ++o) wOp[o] = orn_to_pn[o * NPN + jp];
#pragma unroll
    for (int l = 0; l < NLN; ++l) wLp[l] = ln_to_pn[l * NPN + jp];

    const ulonglong2* inm = gAB + (long)row * NSTEPS;
    unsigned long long* outm = gPN + (long)row * NSTEPS;

    float v_pn = 0.f;
    ulonglong2 ab = inm[0];   // prefetch t=0

    for (int t = 0; t < NSTEPS; ++t) {
        ulonglong2 abn;
        if (t < NSTEPS - 1) abn = inm[t + 1];   // prefetch next step

        const unsigned int mo_lo = (unsigned int)ab.x;
        const unsigned int mo_hi = (unsigned int)(ab.x >> 32);
        const unsigned int ml_lo = (unsigned int)ab.y;
        const unsigned int ml_hi = (unsigned int)(ab.y >> 32);

        // PN excitation: dense ascending-o (exact: s in {0,1})
        float apn = 0.f;
#pragma unroll
        for (int o = 0; o < 32; ++o) apn += (float)((mo_lo >> o) & 1u) * wOp[o];
#pragma unroll
        for (int o = 32; o < NORN; ++o) apn += (float)((mo_hi >> (o - 32)) & 1u) * wOp[o];

        // PN inhibition: dense ascending-l
        float h = 0.f;
#pragma unroll
        for (int l = 0; l < 32; ++l) h += (float)((ml_lo >> l) & 1u) * wLp[l];
#pragma unroll
        for (int l = 32; l < NLN; ++l) h += (float)((ml_hi >> (l - 32)) & 1u) * wLp[l];

        bool sp = false;
        if (lane < NPN) {
            v_pn = ALPHA * v_pn + apn - h;
            sp = (v_pn - VTH) > 0.f;
            if (sp) v_pn = 0.f;
        }
        const unsigned long long mPn = __ballot(sp);
        if (lane == 0) outm[t] = mPn;
        ab = abn;
    }
}

// ===================== Phase 2: KC two-compartment + APL + logits =====================
// (R5/R9/R13-proven 93-95 us / absmax 0.0 — unchanged)
__global__ __launch_bounds__(TPB)
void phase2_kernel(const unsigned long long* __restrict__ g_masks, // [B,20]
                   const float* __restrict__ pn_to_kc,  // [42,2000]
                   const float* __restrict__ kc_to_apl, // [2000,1]
                   const float* __restrict__ apl_to_kc, // [1,2000]
                   const float* __restrict__ dec_w,     // [2000,34]
                   const float* __restrict__ dec_b,     // [34]
                   float* __restrict__ out)             // [B,34]
{
    __shared__ float sRed[2][4];
    __shared__ float sRed2[4 * NOD];

    const int tid  = threadIdx.x;
    const int lane = tid & 63;
    const int wid  = tid >> 6;
    const int b    = blockIdx.x;

    const int  kbase = tid * KPER;
    const bool act   = (kbase < NKC);   // tid < 250
    float vd[KPER], va[KPER], cnt[KPER], wa2k[KPER], wk2a[KPER];
#pragma unroll
    for (int j = 0; j < KPER; ++j) { vd[j] = 0.f; va[j] = 0.f; cnt[j] = 0.f; }
    {
        const float4* a4 = (const float4*)(apl_to_kc + (act ? kbase : 0));
        const float4* k4 = (const float4*)(kc_to_apl + (act ? kbase : 0));
        float4 a0 = a4[0], a1 = a4[1], k0 = k4[0], k1 = k4[1];
        const float g = act ? 1.f : 0.f;
        wa2k[0] = g * a0.x; wa2k[1] = g * a0.y; wa2k[2] = g * a0.z; wa2k[3] = g * a0.w;
        wa2k[4] = g * a1.x; wa2k[5] = g * a1.y; wa2k[6] = g * a1.z; wa2k[7] = g * a1.w;
        wk2a[0] = g * k0.x; wk2a[1] = g * k0.y; wk2a[2] = g * k0.z; wk2a[3] = g * k0.w;
        wk2a[4] = g * k1.x; wk2a[5] = g * k1.y; wk2a[6] = g * k1.z; wk2a[7] = g * k1.w;
    }
    if (tid < 8) sRed[tid >> 2][tid & 3] = 0.f;   // zero both buffers
    __syncthreads();

    const unsigned long long* gm = g_masks + (long)b * NSTEPS;

    for (int t = 0; t < NSTEPS; ++t) {
        const float* rp = sRed[(t + 1) & 1];
        const float apl = fmaxf(rp[0] + rp[1] + rp[2] + rp[3], 0.f);

#pragma unroll
        for (int j = 0; j < KPER; ++j) vd[j] = ALPHA * vd[j] - apl * wa2k[j];

        unsigned long long m = gm[t];   // wave-uniform scalar load
        while (m) {
            const int p0 = __builtin_ctzll(m); m &= m - 1;
            int p1 = p0; float f1 = 0.f;
            if (m) { p1 = __builtin_ctzll(m); m &= m - 1; f1 = 1.f; }
            if (act) {
                const float4* w0 = (const float4*)(pn_to_kc + (long)p0 * NKC + kbase);
                const float4* w1 = (const float4*)(pn_to_kc + (long)p1 * NKC + kbase);
                float4 a0 = w0[0], a1 = w0[1];
                float4 b0 = w1[0], b1 = w1[1];
                vd[0] += a0.x; vd[1] += a0.y; vd[2] += a0.z; vd[3] += a0.w;
                vd[4] += a1.x; vd[5] += a1.y; vd[6] += a1.z; vd[7] += a1.w;
                vd[0] += f1 * b0.x; vd[1] += f1 * b0.y; vd[2] += f1 * b0.z; vd[3] += f1 * b0.w;
                vd[4] += f1 * b1.x; vd[5] += f1 * b1.y; vd[6] += f1 * b1.z; vd[7] += f1 * b1.w;
            }
        }

        float aplp = 0.f;
#pragma unroll
        for (int j = 0; j < KPER; ++j) {
            va[j] = ALPHA * va[j] + GSOMA * (vd[j] - va[j]);
            float s = (va[j] - VTH) > 0.f ? 1.f : 0.f;
            va[j] *= (1.f - s);
            cnt[j] += s;
            aplp += s * wk2a[j];
        }
        for (int off = 32; off > 0; off >>= 1) aplp += __shfl_xor(aplp, off, 64);
        if (lane == 0) sRed[t & 1][wid] = aplp;
        __syncthreads();
    }

    float acc[NOD];
#pragma unroll
    for (int o = 0; o < NOD; ++o) acc[o] = 0.f;
    if (act) {
#pragma unroll
        for (int j = 0; j < KPER; ++j) {
            float r = cnt[j] / 20.0f;
            if (r != 0.f) {
                const float* wr = dec_w + (long)(kbase + j) * NOD;
#pragma unroll
                for (int o = 0; o < NOD; ++o) acc[o] += r * wr[o];
            }
        }
    }
#pragma unroll
    for (int o = 0; o < NOD; ++o) {
        float v = acc[o];
        for (int off = 32; off > 0; off >>= 1) v += __shfl_xor(v, off, 64);
        if (lane == 0) sRed2[wid * NOD + o] = v;
    }
    __syncthreads();
    if (tid < NOD) {
        float v = sRed2[tid] + sRed2[NOD + tid] + sRed2[2 * NOD + tid] +
                  sRed2[3 * NOD + tid] + dec_b[tid];
        out[(long)b * NOD + tid] = v;
    }
}

// ===================== Fallback: round-1 fused kernel (proven) =====================
__global__ __launch_bounds__(TPB)
void snn_fused(const float* __restrict__ or_input, const float* __restrict__ or_gains,
               const float* __restrict__ mapping, const float* __restrict__ orn_to_pn,
               const float* __restrict__ orn_to_ln, const float* __restrict__ ln_to_pn,
               const float* __restrict__ pn_to_kc, const float* __restrict__ kc_to_apl,
               const float* __restrict__ apl_to_kc, const float* __restrict__ dec_w,
               const float* __restrict__ dec_b, float* __restrict__ out)
{
    __shared__ float sW_ol[NORN * NLN];
    __shared__ float sW_op[NORN * NPN];
    __shared__ float sW_lp[NLN * NPN];
    __shared__ float sDrive[NORN];
    __shared__ float sSpg[NOR];
    __shared__ float sOrn[NORN];
    __shared__ float sLn[NLN];
    __shared__ float sApl;
    __shared__ float sRed[4];
    __shared__ float sRed2[4 * NOD];
    __shared__ unsigned long long sMask;

    const int tid = threadIdx.x;
    const int b   = blockIdx.x;

    for (int i = tid; i < NORN * NLN; i += TPB) sW_ol[i] = orn_to_ln[i];
    for (int i = tid; i < NORN * NPN; i += TPB) sW_op[i] = orn_to_pn[i];
    for (int i = tid; i < NLN * NPN;  i += TPB) sW_lp[i] = ln_to_pn[i];
    if (tid < NOR) sSpg[tid] = log1pf(expf(or_gains[tid]));
    if (tid == 0)  sApl = 0.f;
    __syncthreads();

    if (tid < NORN) {
        const float* x = or_input + (long)b * NOR;
        float d = 0.f;
        for (int i = 0; i < NOR; ++i) d += x[i] * sSpg[i] * mapping[i * NORN + tid];
        sDrive[tid] = d * ISCALE;
    }

    const int  kbase = tid * KPER;
    const bool act   = (kbase < NKC);
    float vd[KPER], va[KPER], cnt[KPER], wa2k[KPER], wk2a[KPER];
#pragma unroll
    for (int j = 0; j < KPER; ++j) {
        vd[j] = 0.f; va[j] = 0.f; cnt[j] = 0.f;
        wa2k[j] = act ? apl_to_kc[kbase + j] : 0.f;
        wk2a[j] = act ? kc_to_apl[kbase + j] : 0.f;
    }
    float v_orn = 0.f, v_ln = 0.f, v_pn = 0.f, v_pn_exc = 0.f;
    __syncthreads();

    for (int t = 0; t < NSTEPS; ++t) {
        if (tid < NORN) {
            v_orn = ALPHA * v_orn + sDrive[tid];
            float s = (v_orn - VTH) > 0.f ? 1.f : 0.f;
            v_orn *= (1.f - s);
            sOrn[tid] = s;
        }
        __syncthreads();
        if (tid < NLN) {
            float a = 0.f;
            for (int o = 0; o < NORN; ++o) a += sOrn[o] * sW_ol[o * NLN + tid];
            v_ln = ALPHA * v_ln + a;
            float s = (v_ln - VTH) > 0.f ? 1.f : 0.f;
            v_ln *= (1.f - s);
            sLn[tid] = s;
        } else if (tid >= 64 && tid < 64 + NPN) {
            const int j = tid - 64;
            float a = 0.f;
            for (int o = 0; o < NORN; ++o) a += sOrn[o] * sW_op[o * NPN + j];
            v_pn_exc = a;
        }
        __syncthreads();
        if (tid >= 64 && tid < 64 + NPN) {
            const int j = tid - 64;
            float inh = 0.f;
            for (int l = 0; l < NLN; ++l) inh += sLn[l] * sW_lp[l * NPN + j];
            v_pn = ALPHA * v_pn + v_pn_exc - inh;
            bool s = (v_pn - VTH) > 0.f;
            if (s) v_pn = 0.f;
            unsigned long long bal = __ballot(s);
            if (tid == 64) sMask = bal;
        }
        __syncthreads();
        {
            const float apl = sApl;
#pragma unroll
            for (int j = 0; j < KPER; ++j) vd[j] = ALPHA * vd[j] - apl * wa2k[j];
            unsigned long long m = sMask;
            while (m) {
                const int p = __builtin_ctzll(m);
                m &= m - 1;
                if (act) {
                    const float4* w = (const float4*)(pn_to_kc + (long)p * NKC + kbase);
                    float4 w0 = w[0], w1 = w[1];
                    vd[0] += w0.x; vd[1] += w0.y; vd[2] += w0.z; vd[3] += w0.w;
                    vd[4] += w1.x; vd[5] += w1.y; vd[6] += w1.z; vd[7] += w1.w;
                }
            }
            float aplp = 0.f;
#pragma unroll
            for (int j = 0; j < KPER; ++j) {
                va[j] = ALPHA * va[j] + GSOMA * (vd[j] - va[j]);
                float s = (va[j] - VTH) > 0.f ? 1.f : 0.f;
                va[j] *= (1.f - s);
                cnt[j] += s;
                aplp += s * wk2a[j];
            }
            for (int off = 32; off > 0; off >>= 1) aplp += __shfl_xor(aplp, off, 64);
            if ((tid & 63) == 0) sRed[tid >> 6] = aplp;
        }
        __syncthreads();
        if (tid == 0) {
            float a = sRed[0] + sRed[1] + sRed[2] + sRed[3];
            sApl = fmaxf(a, 0.f);
        }
    }

    float acc[NOD];
#pragma unroll
    for (int o = 0; o < NOD; ++o) acc[o] = 0.f;
    if (act) {
#pragma unroll
        for (int j = 0; j < KPER; ++j) {
            float r = cnt[j] / 20.0f;
            if (r != 0.f) {
                const float* wr = dec_w + (long)(kbase + j) * NOD;
#pragma unroll
                for (int o = 0; o < NOD; ++o) acc[o] += r * wr[o];
            }
        }
    }
#pragma unroll
    for (int o = 0; o < NOD; ++o) {
        float v = acc[o];
        for (int off = 32; off > 0; off >>= 1) v += __shfl_xor(v, off, 64);
        if ((tid & 63) == 0) sRed2[(tid >> 6) * NOD + o] = v;
    }
    __syncthreads();
    if (tid < NOD) {
        float v = sRed2[tid] + sRed2[NOD + tid] + sRed2[2 * NOD + tid] +
                  sRed2[3 * NOD + tid] + dec_b[tid];
        out[(long)b * NOD + tid] = v;
    }
}

extern "C" void kernel_launch(void* const* d_in, const int* in_sizes, int n_in,
                              void* d_out, int out_size, void* d_ws, size_t ws_size,
                              hipStream_t stream) {
    (void)n_in; (void)out_size;
    const float* or_input  = (const float*)d_in[0];
    const float* or_gains  = (const float*)d_in[1];
    const float* mapping   = (const float*)d_in[2];
    const float* orn_to_pn = (const float*)d_in[3];
    const float* orn_to_ln = (const float*)d_in[4];
    const float* ln_to_pn  = (const float*)d_in[5];
    const float* pn_to_kc  = (const float*)d_in[6];
    const float* kc_to_apl = (const float*)d_in[7];
    const float* apl_to_kc = (const float*)d_in[8];
    const float* dec_w     = (const float*)d_in[9];
    const float* dec_b     = (const float*)d_in[10];
    float* out = (float*)d_out;

    const int batch = in_sizes[0] / NOR;  // 4096
    const size_t needAB = (size_t)batch * NSTEPS * sizeof(ulonglong2);          // 1.31 MB
    const size_t needPN = (size_t)batch * NSTEPS * sizeof(unsigned long long);  // 0.66 MB

    if (ws_size >= needAB + needPN) {
        ulonglong2* gAB = (ulonglong2*)d_ws;
        unsigned long long* gPN = (unsigned long long*)((char*)d_ws + needAB);
        hipLaunchKernelGGL(phase1a, dim3(batch), dim3(64), 0, stream,
                           or_input, or_gains, mapping, orn_to_ln, gAB, batch);
        hipLaunchKernelGGL(phase1b, dim3(batch), dim3(64), 0, stream,
                           orn_to_pn, ln_to_pn, gAB, gPN, batch);
        hipLaunchKernelGGL(phase2_kernel, dim3(batch), dim3(TPB), 0, stream,
                           gPN, pn_to_kc, kc_to_apl, apl_to_kc, dec_w, dec_b, out);
    } else {
        hipLaunchKernelGGL(snn_fused, dim3(batch), dim3(TPB), 0, stream,
                           or_input, or_gains, mapping, orn_to_pn, orn_to_ln,
                           ln_to_pn, pn_to_kc, kc_to_apl, apl_to_kc, dec_w, dec_b, out);
    }
}